// Round 1
// baseline (234.017 us; speedup 1.0000x reference)
//
#include <hip/hip_runtime.h>
#include <hip/hip_bf16.h>

// Problem: B=4, H=8, L=128, D=64.  All fp32.
// Layout: X[b][h][l][d] flat = ((b*8+h)*128+l)*64+d ; n = b*8+h in [0,32)

#define EPS 1e-6f
#define BN_EPS 1e-5f

// ---------------------------------------------------------------- K1
// One wave (64 threads) per (b,h,l) row: softmax(Q), softmax(K),
// Vn/entropy(V). grid = 4096, block = 64.
__global__ void k1_softmax_entropy(const float* __restrict__ Q,
                                   const float* __restrict__ K,
                                   const float* __restrict__ V,
                                   float* __restrict__ pQ,
                                   float* __restrict__ pK,
                                   float* __restrict__ hi,
                                   float* __restrict__ h_raw) {
    const int r = blockIdx.x;          // (b*8+h)*128 + l
    const int d = threadIdx.x;         // 0..63
    const int base = r * 64 + d;

    // softmax over Q row
    float q = Q[base];
    float m = q;
    for (int off = 32; off > 0; off >>= 1) m = fmaxf(m, __shfl_xor(m, off));
    float e = expf(q - m);
    float s = e;
    for (int off = 32; off > 0; off >>= 1) s += __shfl_xor(s, off);
    pQ[base] = e / s;

    // softmax over K row
    float kk = K[base];
    m = kk;
    for (int off = 32; off > 0; off >>= 1) m = fmaxf(m, __shfl_xor(m, off));
    e = expf(kk - m);
    s = e;
    for (int off = 32; off > 0; off >>= 1) s += __shfl_xor(s, off);
    pK[base] = e / s;

    // V entropy
    float v = V[base];
    s = v;
    for (int off = 32; off > 0; off >>= 1) s += __shfl_xor(s, off);
    float vn = v / (s + EPS);
    vn = fminf(fmaxf(vn, EPS), 1.0f);
    float hv = -vn * log2f(vn);
    hi[base] = hv;
    float hs = hv;
    for (int off = 32; off > 0; off >>= 1) hs += __shfl_xor(hs, off);
    if (d == 0) h_raw[r] = hs;
}

// ---------------------------------------------------------------- K2
// J matrix. One block per (n, i-tile of 8 rows): grid = 32*16 = 512,
// block = 256. pK slice (128x64) staged in LDS padded to 65 floats/row
// (2-way bank aliasing only -> free). 4 (i,j) pairs per thread.
#define IT 8
__global__ void k2_J(const float* __restrict__ pQ,
                     const float* __restrict__ pK,
                     float* __restrict__ J) {
    __shared__ float sK[128 * 65];
    __shared__ float sQ[IT * 64];
    const int bid = blockIdx.x;        // n*16 + it
    const int n = bid >> 4;
    const int i0 = (bid & 15) * IT;
    const int tid = threadIdx.x;       // 0..255

    const float* pKb = pK + n * 8192;
    const float* pQb = pQ + n * 8192 + i0 * 64;
    for (int k = tid; k < 8192; k += 256)
        sK[(k >> 6) * 65 + (k & 63)] = pKb[k];
    for (int k = tid; k < IT * 64; k += 256)
        sQ[k] = pQb[k];
    __syncthreads();

    for (int s = 0; s < (IT * 128) / 256; ++s) {
        const int p = tid + 256 * s;
        const int il = p >> 7;         // 0..7
        const int j = p & 127;
        const float* qrow = sQ + il * 64;
        const float* krow = sK + j * 65;
        float klq = 0.f, klk = 0.f;
        for (int d = 0; d < 64; ++d) {
            const float q = qrow[d];
            const float k = krow[d];
            const float im = 1.0f / (0.5f * (q + k) + EPS);
            klq += q * log2f(q * im + EPS);
            klk += k * log2f(k * im + EPS);
        }
        J[(n * 128 + i0 + il) * 128 + j] = 0.5f * klq + 0.5f * klk;
    }
}

// ---------------------------------------------------------------- K3
// Off-diagonal J stats per head (mean, invstd), double precision,
// deterministic. grid = 8 (one block per head), block = 256.
__global__ void k3_jstats(const float* __restrict__ J,
                          float* __restrict__ jstats) {  // [0..7]=mean [8..15]=invstd
    __shared__ double sd[256], sd2[256];
    const int h = blockIdx.x;
    const int tid = threadIdx.x;
    double s = 0.0, s2 = 0.0;
    for (int idx = tid; idx < 65536; idx += 256) {
        const int b = idx >> 14;
        const int rem = idx & 16383;
        const int i = rem >> 7;
        const int j = rem & 127;
        if (i == j) continue;
        const float v = J[((b * 8 + h) * 128 + i) * 128 + j];
        s += v;
        s2 += (double)v * (double)v;
    }
    sd[tid] = s; sd2[tid] = s2;
    __syncthreads();
    for (int off = 128; off > 0; off >>= 1) {
        if (tid < off) { sd[tid] += sd[tid + off]; sd2[tid] += sd2[tid + off]; }
        __syncthreads();
    }
    if (tid == 0) {
        const double cnt = 65024.0;    // 4*128*127
        const double mean = sd[0] / cnt;
        const double var = sd2[0] / cnt - mean * mean;
        jstats[h] = (float)mean;
        jstats[8 + h] = (float)(1.0 / sqrt(var + (double)BN_EPS));
    }
}

// ---------------------------------------------------------------- K3b
// Batch-norm of h per head over B*L = 512 values. grid = 8, block = 512.
__global__ void k3b_hbn(const float* __restrict__ h_raw,
                        const float* __restrict__ h_gamma,
                        const float* __restrict__ h_beta,
                        float* __restrict__ h_bn) {
    __shared__ double sd[512], sd2[512];
    const int hh = blockIdx.x;
    const int tid = threadIdx.x;       // 0..511
    const int b = tid >> 7, l = tid & 127;
    const float v = h_raw[(b * 8 + hh) * 128 + l];
    sd[tid] = v; sd2[tid] = (double)v * (double)v;
    __syncthreads();
    for (int off = 256; off > 0; off >>= 1) {
        if (tid < off) { sd[tid] += sd[tid + off]; sd2[tid] += sd2[tid + off]; }
        __syncthreads();
    }
    const double mean = sd[0] / 512.0;
    const double var = sd2[0] / 512.0 - mean * mean;
    const float invstd = (float)(1.0 / sqrt(var + (double)BN_EPS));
    h_bn[(b * 8 + hh) * 128 + l] =
        (v - (float)mean) * invstd * h_gamma[hh] + h_beta[hh];
}

// ---------------------------------------------------------------- K4
// Normalize off-diag J (in place), row-sum, gate x. grid = 4096, block = 128.
__global__ void k4_norm_x(float* __restrict__ J,
                          const float* __restrict__ jstats,
                          const float* __restrict__ j_gamma,
                          const float* __restrict__ j_beta,
                          const float* __restrict__ h_bn,
                          float* __restrict__ x) {
    __shared__ float ssum[2];
    const int r = blockIdx.x;          // n*128 + i
    const int j = threadIdx.x;         // 0..127
    const int i = r & 127;
    const int hh = (r >> 7) & 7;
    float v = J[r * 128 + j];
    if (j != i)
        v = (v - jstats[hh]) * jstats[8 + hh] * j_gamma[hh] + j_beta[hh];
    J[r * 128 + j] = v;
    float s = v;
    for (int off = 32; off > 0; off >>= 1) s += __shfl_xor(s, off);
    if ((j & 63) == 0) ssum[j >> 6] = s;
    __syncthreads();
    if (j == 0)
        x[r] = (ssum[0] + ssum[1] + h_bn[r] < 0.0f) ? 1.0f : 0.0f;
}

// ---------------------------------------------------------------- K5
// He and pre-BN t = -(He*hi/h). grid = 4096, block = 128.
__global__ void k5_hd(const float* __restrict__ J,
                      const float* __restrict__ x,
                      const float* __restrict__ h_bn,
                      const float* __restrict__ hi,
                      float* __restrict__ t) {
    __shared__ float ssum[2];
    __shared__ float sHe;
    const int r = blockIdx.x;
    const int tid = threadIdx.x;       // 0..127
    const int n = r >> 7;
    float s = J[r * 128 + tid] * x[n * 128 + tid];
    for (int off = 32; off > 0; off >>= 1) s += __shfl_xor(s, off);
    if ((tid & 63) == 0) ssum[tid >> 6] = s;
    __syncthreads();
    if (tid == 0)
        sHe = x[r] * (ssum[0] + ssum[1] + h_bn[r]);
    __syncthreads();
    if (tid < 64) {
        const float He = sHe;
        t[r * 64 + tid] = -(He * hi[r * 64 + tid] / h_bn[r]);
    }
}

// ---------------------------------------------------------------- K6
// t stats per head over B*L*D = 32768. grid = 8, block = 256.
__global__ void k6_tstats(const float* __restrict__ t,
                          float* __restrict__ tstats) { // [0..7]=mean [8..15]=invstd
    __shared__ double sd[256], sd2[256];
    const int hh = blockIdx.x;
    const int tid = threadIdx.x;
    double s = 0.0, s2 = 0.0;
    for (int idx = tid; idx < 32768; idx += 256) {
        const int b = idx >> 13;
        const int rem = idx & 8191;
        const float v = t[(b * 8 + hh) * 8192 + rem];
        s += v;
        s2 += (double)v * (double)v;
    }
    sd[tid] = s; sd2[tid] = s2;
    __syncthreads();
    for (int off = 128; off > 0; off >>= 1) {
        if (tid < off) { sd[tid] += sd[tid + off]; sd2[tid] += sd2[tid + off]; }
        __syncthreads();
    }
    if (tid == 0) {
        const double mean = sd[0] / 32768.0;
        const double var = sd2[0] / 32768.0 - mean * mean;
        tstats[hh] = (float)mean;
        tstats[8 + hh] = (float)(1.0 / sqrt(var + (double)BN_EPS));
    }
}

// ---------------------------------------------------------------- K7
// Final BN write. grid = 1024, block = 256.
__global__ void k7_out(const float* __restrict__ t,
                       const float* __restrict__ tstats,
                       const float* __restrict__ gamma,
                       const float* __restrict__ beta,
                       float* __restrict__ out) {
    const int g = blockIdx.x * 256 + threadIdx.x;
    const int hh = (g >> 13) & 7;      // flat = (b*8+h)*8192 + rem
    out[g] = (t[g] - tstats[hh]) * tstats[8 + hh] * gamma[hh] + beta[hh];
}

// ---------------------------------------------------------------- launch
extern "C" void kernel_launch(void* const* d_in, const int* in_sizes, int n_in,
                              void* d_out, int out_size, void* d_ws, size_t ws_size,
                              hipStream_t stream) {
    const float* Q = (const float*)d_in[0];
    const float* K = (const float*)d_in[1];
    const float* V = (const float*)d_in[2];
    const float* j_gamma = (const float*)d_in[3];
    const float* j_beta  = (const float*)d_in[4];
    const float* h_gamma = (const float*)d_in[5];
    const float* h_beta  = (const float*)d_in[6];
    const float* bnH_gamma = (const float*)d_in[7];
    const float* bnH_beta  = (const float*)d_in[8];
    float* out = (float*)d_out;

    float* w = (float*)d_ws;
    float* pQ    = w;                  // 262144
    float* pK    = w + 262144;         // 262144
    float* hi    = w + 524288;         // 262144
    float* J     = w + 786432;         // 524288
    float* t     = w + 1310720;        // 262144
    float* h_raw = w + 1572864;        // 4096
    float* h_bn  = w + 1576960;        // 4096
    float* x     = w + 1581056;        // 4096
    float* jstats = w + 1585152;       // 16
    float* tstats = w + 1585168;       // 16

    k1_softmax_entropy<<<4096, 64, 0, stream>>>(Q, K, V, pQ, pK, hi, h_raw);
    k2_J<<<512, 256, 0, stream>>>(pQ, pK, J);
    k3_jstats<<<8, 256, 0, stream>>>(J, jstats);
    k3b_hbn<<<8, 512, 0, stream>>>(h_raw, h_gamma, h_beta, h_bn);
    k4_norm_x<<<4096, 128, 0, stream>>>(J, jstats, j_gamma, j_beta, h_bn, x);
    k5_hd<<<4096, 128, 0, stream>>>(J, x, h_bn, hi, t);
    k6_tstats<<<8, 256, 0, stream>>>(t, tstats);
    k7_out<<<1024, 256, 0, stream>>>(t, tstats, bnH_gamma, bnH_beta, out);
}

// Round 2
// 122.547 us; speedup vs baseline: 1.9096x; 1.9096x over previous
//
#include <hip/hip_runtime.h>
#include <hip/hip_bf16.h>

// Problem: B=4, H=8, L=128, D=64.  All fp32.
// Layout: X[b][h][l][d] flat = ((b*8+h)*128+l)*64+d ; n = b*8+h in [0,32)

#define EPS 1e-6f
#define BN_EPS 1e-5f

// ---------------------------------------------------------------- K1
// One wave (64 threads) per (b,h,l) row: softmax(Q), softmax(K),
// Vn/entropy(V). grid = 4096, block = 64.
__global__ void k1_softmax_entropy(const float* __restrict__ Q,
                                   const float* __restrict__ K,
                                   const float* __restrict__ V,
                                   float* __restrict__ pQ,
                                   float* __restrict__ pK,
                                   float* __restrict__ hi,
                                   float* __restrict__ h_raw) {
    const int r = blockIdx.x;          // (b*8+h)*128 + l
    const int d = threadIdx.x;         // 0..63
    const int base = r * 64 + d;

    // softmax over Q row
    float q = Q[base];
    float m = q;
    for (int off = 32; off > 0; off >>= 1) m = fmaxf(m, __shfl_xor(m, off));
    float e = expf(q - m);
    float s = e;
    for (int off = 32; off > 0; off >>= 1) s += __shfl_xor(s, off);
    pQ[base] = e / s;

    // softmax over K row
    float kk = K[base];
    m = kk;
    for (int off = 32; off > 0; off >>= 1) m = fmaxf(m, __shfl_xor(m, off));
    e = expf(kk - m);
    s = e;
    for (int off = 32; off > 0; off >>= 1) s += __shfl_xor(s, off);
    pK[base] = e / s;

    // V entropy
    float v = V[base];
    s = v;
    for (int off = 32; off > 0; off >>= 1) s += __shfl_xor(s, off);
    float vn = v / (s + EPS);
    vn = fminf(fmaxf(vn, EPS), 1.0f);
    float hv = -vn * log2f(vn);
    hi[base] = hv;
    float hs = hv;
    for (int off = 32; off > 0; off >>= 1) hs += __shfl_xor(hs, off);
    if (d == 0) h_raw[r] = hs;
}

// ---------------------------------------------------------------- K2
// J matrix + fused per-block partial (sum, sumsq) of off-diag J in double.
// One block per (n, i-tile of 8 rows): grid = 32*16 = 512, block = 256.
// pK slice (128x64) staged in LDS padded to 65 floats/row (2-way bank
// aliasing only -> free). 4 (i,j) pairs per thread.
#define IT 8
__global__ void k2_J(const float* __restrict__ pQ,
                     const float* __restrict__ pK,
                     float* __restrict__ J,
                     double* __restrict__ Jpart) {
    __shared__ float sK[128 * 65];
    __shared__ float sQ[IT * 64];
    __shared__ double rs[256], rs2[256];
    const int bid = blockIdx.x;        // n*16 + it
    const int n = bid >> 4;
    const int i0 = (bid & 15) * IT;
    const int tid = threadIdx.x;       // 0..255

    const float* pKb = pK + n * 8192;
    const float* pQb = pQ + n * 8192 + i0 * 64;
    for (int k = tid; k < 8192; k += 256)
        sK[(k >> 6) * 65 + (k & 63)] = pKb[k];
    for (int k = tid; k < IT * 64; k += 256)
        sQ[k] = pQb[k];
    __syncthreads();

    double ls = 0.0, ls2 = 0.0;
    for (int s = 0; s < (IT * 128) / 256; ++s) {
        const int p = tid + 256 * s;
        const int il = p >> 7;         // 0..7
        const int j = p & 127;
        const float* qrow = sQ + il * 64;
        const float* krow = sK + j * 65;
        float klq = 0.f, klk = 0.f;
        for (int d = 0; d < 64; ++d) {
            const float q = qrow[d];
            const float k = krow[d];
            const float im = 1.0f / (0.5f * (q + k) + EPS);
            klq += q * log2f(q * im + EPS);
            klk += k * log2f(k * im + EPS);
        }
        const float v = 0.5f * klq + 0.5f * klk;
        J[(n * 128 + i0 + il) * 128 + j] = v;
        if (j != i0 + il) {            // exclude diagonal from BN stats
            ls += v;
            ls2 += (double)v * (double)v;
        }
    }
    rs[tid] = ls; rs2[tid] = ls2;
    __syncthreads();
    for (int off = 128; off > 0; off >>= 1) {
        if (tid < off) { rs[tid] += rs[tid + off]; rs2[tid] += rs2[tid + off]; }
        __syncthreads();
    }
    if (tid == 0) {
        Jpart[2 * bid] = rs[0];
        Jpart[2 * bid + 1] = rs2[0];
    }
}

// ---------------------------------------------------------------- K3
// Combine J partials -> jstats (per-head mean, invstd), AND do the h
// batch-norm (fused, replaces old k3b). grid = 8, block = 64.
__global__ void k3_stats(const double* __restrict__ Jpart,
                         const float* __restrict__ h_raw,
                         const float* __restrict__ h_gamma,
                         const float* __restrict__ h_beta,
                         float* __restrict__ jstats,   // [0..7]=mean [8..15]=invstd
                         float* __restrict__ h_bn) {
    __shared__ double sd[64], sd2[64];
    const int h = blockIdx.x;
    const int t = threadIdx.x;         // 0..63

    // --- J stats: 64 partials for this head (4 b's x 16 tiles) ---
    const int bI = t >> 4, it = t & 15;
    const int bid = (bI * 8 + h) * 16 + it;
    sd[t] = Jpart[2 * bid];
    sd2[t] = Jpart[2 * bid + 1];
    __syncthreads();
    for (int off = 32; off > 0; off >>= 1) {
        if (t < off) { sd[t] += sd[t + off]; sd2[t] += sd2[t + off]; }
        __syncthreads();
    }
    if (t == 0) {
        const double cnt = 65024.0;    // 4*128*127
        const double mean = sd[0] / cnt;
        const double var = sd2[0] / cnt - mean * mean;
        jstats[h] = (float)mean;
        jstats[8 + h] = (float)(1.0 / sqrt(var + (double)BN_EPS));
    }
    __syncthreads();

    // --- h batch-norm over B*L = 512 values for this head ---
    float hv[8];
    double hs = 0.0, hs2 = 0.0;
    for (int k = 0; k < 8; ++k) {
        const int idx = t * 8 + k;     // 0..511
        const int b = idx >> 7, l = idx & 127;
        const float v = h_raw[(b * 8 + h) * 128 + l];
        hv[k] = v;
        hs += v;
        hs2 += (double)v * (double)v;
    }
    sd[t] = hs; sd2[t] = hs2;
    __syncthreads();
    for (int off = 32; off > 0; off >>= 1) {
        if (t < off) { sd[t] += sd[t + off]; sd2[t] += sd2[t + off]; }
        __syncthreads();
    }
    const double hm = sd[0] / 512.0;
    const double hvar = sd2[0] / 512.0 - hm * hm;
    const float hinv = (float)(1.0 / sqrt(hvar + (double)BN_EPS));
    const float g = h_gamma[h], be = h_beta[h];
    for (int k = 0; k < 8; ++k) {
        const int idx = t * 8 + k;
        const int b = idx >> 7, l = idx & 127;
        h_bn[(b * 8 + h) * 128 + l] = (hv[k] - (float)hm) * hinv * g + be;
    }
}

// ---------------------------------------------------------------- K4
// Normalize off-diag J (in place), row-sum, gate x. grid = 4096, block = 128.
__global__ void k4_norm_x(float* __restrict__ J,
                          const float* __restrict__ jstats,
                          const float* __restrict__ j_gamma,
                          const float* __restrict__ j_beta,
                          const float* __restrict__ h_bn,
                          float* __restrict__ x) {
    __shared__ float ssum[2];
    const int r = blockIdx.x;          // n*128 + i
    const int j = threadIdx.x;         // 0..127
    const int i = r & 127;
    const int hh = (r >> 7) & 7;
    float v = J[r * 128 + j];
    if (j != i)
        v = (v - jstats[hh]) * jstats[8 + hh] * j_gamma[hh] + j_beta[hh];
    J[r * 128 + j] = v;
    float s = v;
    for (int off = 32; off > 0; off >>= 1) s += __shfl_xor(s, off);
    if ((j & 63) == 0) ssum[j >> 6] = s;
    __syncthreads();
    if (j == 0)
        x[r] = (ssum[0] + ssum[1] + h_bn[r] < 0.0f) ? 1.0f : 0.0f;
}

// ---------------------------------------------------------------- K5
// He, pre-BN t = -(He*hi/h), fused per-row double partial (sum, sumsq).
// grid = 4096, block = 64 (one wave per row).
__global__ void k5_hd(const float* __restrict__ J,
                      const float* __restrict__ x,
                      const float* __restrict__ h_bn,
                      const float* __restrict__ hi,
                      float* __restrict__ t,
                      double* __restrict__ tpart) {
    const int r = blockIdx.x;
    const int tid = threadIdx.x;       // 0..63
    const int n = r >> 7;
    const float* xr = x + n * 128;
    float s = J[r * 128 + tid] * xr[tid] + J[r * 128 + 64 + tid] * xr[64 + tid];
    for (int off = 32; off > 0; off >>= 1) s += __shfl_xor(s, off);
    const float He = x[r] * (s + h_bn[r]);
    const float tv = -(He * hi[r * 64 + tid] / h_bn[r]);
    t[r * 64 + tid] = tv;
    double ds = tv, ds2 = (double)tv * (double)tv;
    for (int off = 32; off > 0; off >>= 1) {
        ds += __shfl_xor(ds, off);
        ds2 += __shfl_xor(ds2, off);
    }
    if (tid == 0) {
        tpart[2 * r] = ds;
        tpart[2 * r + 1] = ds2;
    }
}

// ---------------------------------------------------------------- K6
// Combine t partials -> tstats per head (512 partials/head).
// grid = 8, block = 256.
__global__ void k6_tstats(const double* __restrict__ tpart,
                          float* __restrict__ tstats) { // [0..7]=mean [8..15]=invstd
    __shared__ double sd[256], sd2[256];
    const int hh = blockIdx.x;
    const int tid = threadIdx.x;
    double s = 0.0, s2 = 0.0;
    for (int p = tid; p < 512; p += 256) {
        const int b = p >> 7, i = p & 127;
        const int r = (b * 8 + hh) * 128 + i;
        s += tpart[2 * r];
        s2 += tpart[2 * r + 1];
    }
    sd[tid] = s; sd2[tid] = s2;
    __syncthreads();
    for (int off = 128; off > 0; off >>= 1) {
        if (tid < off) { sd[tid] += sd[tid + off]; sd2[tid] += sd2[tid + off]; }
        __syncthreads();
    }
    if (tid == 0) {
        const double mean = sd[0] / 32768.0;
        const double var = sd2[0] / 32768.0 - mean * mean;
        tstats[hh] = (float)mean;
        tstats[8 + hh] = (float)(1.0 / sqrt(var + (double)BN_EPS));
    }
}

// ---------------------------------------------------------------- K7
// Final BN write. grid = 1024, block = 256.
__global__ void k7_out(const float* __restrict__ t,
                       const float* __restrict__ tstats,
                       const float* __restrict__ gamma,
                       const float* __restrict__ beta,
                       float* __restrict__ out) {
    const int g = blockIdx.x * 256 + threadIdx.x;
    const int hh = (g >> 13) & 7;      // flat = (b*8+h)*8192 + rem
    out[g] = (t[g] - tstats[hh]) * tstats[8 + hh] * gamma[hh] + beta[hh];
}

// ---------------------------------------------------------------- launch
extern "C" void kernel_launch(void* const* d_in, const int* in_sizes, int n_in,
                              void* d_out, int out_size, void* d_ws, size_t ws_size,
                              hipStream_t stream) {
    const float* Q = (const float*)d_in[0];
    const float* K = (const float*)d_in[1];
    const float* V = (const float*)d_in[2];
    const float* j_gamma = (const float*)d_in[3];
    const float* j_beta  = (const float*)d_in[4];
    const float* h_gamma = (const float*)d_in[5];
    const float* h_beta  = (const float*)d_in[6];
    const float* bnH_gamma = (const float*)d_in[7];
    const float* bnH_beta  = (const float*)d_in[8];
    float* out = (float*)d_out;

    float* w = (float*)d_ws;
    float* pQ    = w;                  // 262144 floats (dead after k2)
    float* pK    = w + 262144;         // 262144
    float* hi    = w + 524288;         // 262144
    float* J     = w + 786432;         // 524288
    float* t     = w + 1310720;        // 262144 (written in k5)
    float* h_raw = w + 1572864;        // 4096
    float* h_bn  = w + 1576960;        // 4096
    float* x     = w + 1581056;        // 4096
    float* jstats = w + 1585152;       // 16
    float* tstats = w + 1585168;       // 16
    // Partial buffers overlap dead regions (no extra ws use):
    //  Jpart: written k2, read k3 — lives where t will later be written (k5).
    //  tpart: written k5, read k6 — lives where pQ was (dead after k2).
    double* Jpart = (double*)(w + 1310720);  // 1024 doubles (8 KB)
    double* tpart = (double*)(w);            // 8192 doubles (64 KB)

    k1_softmax_entropy<<<4096, 64, 0, stream>>>(Q, K, V, pQ, pK, hi, h_raw);
    k2_J<<<512, 256, 0, stream>>>(pQ, pK, J, Jpart);
    k3_stats<<<8, 64, 0, stream>>>(Jpart, h_raw, h_gamma, h_beta, jstats, h_bn);
    k4_norm_x<<<4096, 128, 0, stream>>>(J, jstats, j_gamma, j_beta, h_bn, x);
    k5_hd<<<4096, 64, 0, stream>>>(J, x, h_bn, hi, t, tpart);
    k6_tstats<<<8, 256, 0, stream>>>(tpart, tstats);
    k7_out<<<1024, 256, 0, stream>>>(t, tstats, bnH_gamma, bnH_beta, out);
}